// Round 1
// baseline (19384.909 us; speedup 1.0000x reference)
//
#include <hip/hip_runtime.h>

// MixedLayerCond: per-sample branch-selected conv (k in {1,3,5,7}, SAME, NCHW)
// + class-embedding bias. Only the selected branch is computed (4x FLOP cut vs
// reference's compute-all-and-mask).
//
// Round 0: direct conv, fp32 VALU. Block = (sample b, 16-out-channel chunk).
// 256 threads; thread t owns spatial col=t&31, rows {t>>5, +8, +16, +24}.
// x staged 8 input-channel planes at a time into LDS (32 KB).

#define CIN   256
#define COUT  256
#define HH    32
#define WW    32
#define HW    1024

__global__ __launch_bounds__(256) void cond_conv_direct(
    const float* __restrict__ x,
    const int*   __restrict__ y,
    const int*   __restrict__ arc,
    const float* __restrict__ w0, const float* __restrict__ e0,
    const float* __restrict__ w1, const float* __restrict__ e1,
    const float* __restrict__ w2, const float* __restrict__ e2,
    const float* __restrict__ w3, const float* __restrict__ e3,
    float* __restrict__ out)
{
    const int b   = blockIdx.x >> 4;          // sample
    const int o0  = (blockIdx.x & 15) << 4;   // out-channel chunk base (16 oc)
    const int tid = threadIdx.x;              // 256
    const int col  = tid & 31;
    const int row0 = tid >> 5;                // 0..7

    // Branch / class selection — force wave-uniform scalar paths.
    int a   = arc[b];
    int cls = y[b];
    a   = __builtin_amdgcn_readfirstlane(a);
    cls = __builtin_amdgcn_readfirstlane(cls);

    const int k   = (a == 0) ? 1 : (a == 1) ? 3 : (a == 2) ? 5 : 7;
    const int kk  = k * k;
    const int pad = k >> 1;
    const float* __restrict__ wp = (a == 0) ? w0 : (a == 1) ? w1 : (a == 2) ? w2 : w3;
    const float* __restrict__ ep = (a == 0) ? e0 : (a == 1) ? e1 : (a == 2) ? e2 : e3;

    __shared__ float xs[8 * HW];              // 8 input planes, 32 KB

    float acc[16][4];
#pragma unroll
    for (int o = 0; o < 16; ++o)
#pragma unroll
        for (int p = 0; p < 4; ++p) acc[o][p] = 0.f;

    const float* xb = x + (size_t)b * CIN * HW;

    for (int c0 = 0; c0 < CIN; c0 += 8) {
        __syncthreads();                      // previous iter's reads done
        {   // stage 8 contiguous planes: 8192 floats = 2048 float4
            const float4* src = (const float4*)(xb + c0 * HW);
            float4*       dst = (float4*)xs;
#pragma unroll
            for (int i = 0; i < 8; ++i)
                dst[tid + (i << 8)] = src[tid + (i << 8)];
        }
        __syncthreads();

        for (int kh = 0; kh < k; ++kh) {
            const int dh = kh - pad;
            int  raddr[4];
            bool rok[4];
#pragma unroll
            for (int p = 0; p < 4; ++p) {
                const int rr = row0 + 8 * p + dh;
                rok[p]   = (rr >= 0) && (rr < HH);
                raddr[p] = (rok[p] ? rr : 0) * WW;
            }
            for (int kw = 0; kw < k; ++kw) {
                const int  cc   = col + kw - pad;
                const bool cok  = (cc >= 0) && (cc < WW);
                const int  cofs = cok ? cc : 0;
                const int  khw  = kh * k + kw;
#pragma unroll
                for (int ci = 0; ci < 8; ++ci) {
                    float xv[4];
#pragma unroll
                    for (int p = 0; p < 4; ++p) {
                        const float v = xs[ci * HW + raddr[p] + cofs];
                        xv[p] = (rok[p] && cok) ? v : 0.f;
                    }
                    // wave-uniform weight base for this (ci, kh, kw)
                    const float* wb = wp + (size_t)o0 * CIN * kk
                                         + (size_t)(c0 + ci) * kk + khw;
#pragma unroll
                    for (int o = 0; o < 16; ++o) {
                        const float ws = wb[(size_t)o * CIN * kk];  // scalar load
#pragma unroll
                        for (int p = 0; p < 4; ++p)
                            acc[o][p] += ws * xv[p];
                    }
                }
            }
        }
    }

    // Epilogue: add embedding bias, store coalesced.
    const float* erow = ep + (size_t)cls * COUT + o0;
    float* ob = out + ((size_t)b * COUT + o0) * HW;
#pragma unroll
    for (int o = 0; o < 16; ++o) {
        const float ev = erow[o];
#pragma unroll
        for (int p = 0; p < 4; ++p)
            ob[o * HW + (row0 + 8 * p) * WW + col] = acc[o][p] + ev;
    }
}

extern "C" void kernel_launch(void* const* d_in, const int* in_sizes, int n_in,
                              void* d_out, int out_size, void* d_ws, size_t ws_size,
                              hipStream_t stream) {
    const float* x   = (const float*)d_in[0];
    const int*   y   = (const int*)  d_in[1];
    const int*   arc = (const int*)  d_in[2];
    const float* w0  = (const float*)d_in[3];
    const float* e0  = (const float*)d_in[4];
    const float* w1  = (const float*)d_in[5];
    const float* e1  = (const float*)d_in[6];
    const float* w2  = (const float*)d_in[7];
    const float* e2  = (const float*)d_in[8];
    const float* w3  = (const float*)d_in[9];
    const float* e3  = (const float*)d_in[10];
    float* out = (float*)d_out;

    const int B = in_sizes[1];                // y has B elements
    dim3 grid(B * 16), block(256);
    hipLaunchKernelGGL(cond_conv_direct, grid, block, 0, stream,
                       x, y, arc, w0, e0, w1, e1, w2, e2, w3, e3, out);
}

// Round 2
// 507.206 us; speedup vs baseline: 38.2190x; 38.2190x over previous
//
#include <hip/hip_runtime.h>

// MixedLayerCond round 2: bf16 MFMA implicit-GEMM conv, selected branch only.
//
//  Pre-pass 1 (px): x NCHW fp32 -> xt[b][cc][h][w][ci32] bf16   (33.5 MB in ws)
//  Pre-pass 2 (pw): w OIHW fp32 -> wt[a][cc][oc][khw][ci32] bf16 (11.0 MB in ws)
//  Main: per block (sample, 128-oc tile, 8-row spatial tile):
//    K-loop over cc (8 ci-chunks of 32) x khw; x chunk staged once per cc into
//    LDS with zero-filled halo (all k*k shifts read it); A-frags direct from
//    global (L2-hot); 16x16x32 bf16 MFMA, wave tile 64x128.

typedef unsigned short ushort_t;
typedef __attribute__((ext_vector_type(8))) short short8;
typedef __attribute__((ext_vector_type(4))) float f32x4;

#define CIN   256
#define COUT  256
#define HH    32
#define WW    32
#define HW    1024

// ws layout (ushort elements)
#define XT_ELEMS   16777216            // 64*8*1024*32
#define WT_OFF_0   0
#define WT_OFF_1   65536               // 8*256*1*32
#define WT_OFF_2   655360              // + 8*256*9*32
#define WT_OFF_3   2293760             // + 8*256*25*32
#define WT_ELEMS   5505024             // + 8*256*49*32
#define WS_NEEDED  ((size_t)(XT_ELEMS + WT_ELEMS) * 2)

// LDS x tile: 14 rows x 38 cols x ci-stride 40 (pad 32->40 keeps 16B align,
// balances banks: 8 dword accesses per bank per b128 wave-read)
#define XS_R_STRIDE 1520               // 38*40
#define XS_C_STRIDE 40
#define XS_ELEMS    21280              // 14*1520

__device__ inline ushort_t f2bf(float f) {
    unsigned x = __builtin_bit_cast(unsigned, f);
    unsigned r = (x + 0x7FFFu + ((x >> 16) & 1u)) >> 16;
    return (ushort_t)r;
}

// ---------------- pre-pass: x transform ----------------
__global__ __launch_bounds__(256) void px_kernel(const float* __restrict__ x,
                                                 ushort_t* __restrict__ xt) {
    const int id = blockIdx.x * 256 + threadIdx.x;   // 64*8*1024 threads
    const int hw = id & 1023;
    const int cc = (id >> 10) & 7;
    const int b  = id >> 13;
    const float* src = x + ((size_t)(b * CIN + cc * 32)) * HW + hw;
    ushort_t* dst = xt + ((size_t)((b * 8 + cc) * HW + hw)) * 32;
#pragma unroll
    for (int v = 0; v < 4; ++v) {
        short8 o;
#pragma unroll
        for (int j = 0; j < 8; ++j)
            o[j] = (short)f2bf(src[(size_t)(v * 8 + j) * HW]);
        *(short8*)(dst + v * 8) = o;
    }
}

// ---------------- pre-pass: w transform ----------------
__global__ __launch_bounds__(256) void pw_kernel(const float* __restrict__ w,
                                                 ushort_t* __restrict__ wt,
                                                 int kk, int total) {
    const int wid = blockIdx.x * 256 + threadIdx.x;
    if (wid >= total) return;
    const int m   = wid & 31;
    const int r   = wid >> 5;
    const int khw = r % kk;
    const int r2  = r / kk;
    const int oc  = r2 & 255;
    const int cc  = r2 >> 8;
    wt[wid] = f2bf(w[((size_t)(oc * CIN + cc * 32 + m)) * kk + khw]);
}

// ---------------- main: MFMA conv body ----------------
template <int K>
__device__ void conv_body(const ushort_t* __restrict__ xt,
                          const ushort_t* __restrict__ wtb,
                          const float* __restrict__ eb,
                          int b, int cls, int oc0, int r0,
                          float* __restrict__ out, ushort_t* xs) {
    constexpr int KK  = K * K;
    constexpr int PAD = K / 2;
    const int tid  = threadIdx.x;
    const int wave = tid >> 6;
    const int lane = tid & 63;
    const int wm   = wave >> 1;        // oc half within 128-tile
    const int wn   = wave & 1;         // spatial half (128 of 256)
    const int ln   = lane & 15;
    const int q    = lane >> 4;

    f32x4 acc[4][8];
#pragma unroll
    for (int mt = 0; mt < 4; ++mt)
#pragma unroll
        for (int nt = 0; nt < 8; ++nt) acc[mt][nt] = (f32x4)0.0f;

    // zero LDS once (halo cells stay zero forever; interior rewritten per cc)
    {
        short8 z = (short8)0;
        for (int i = tid; i < XS_ELEMS / 8; i += 256)
            *(short8*)&xs[i * 8] = z;
    }

    for (int cc = 0; cc < 8; ++cc) {
        __syncthreads();
        // stage 14 rows x 32 cols x 32 ci (valid cells only) from xt
        const ushort_t* xsrc = xt + ((size_t)(b * 8 + cc)) * (HW * 32);
#pragma unroll
        for (int i = 0; i < 7; ++i) {
            const int id = tid + i * 256;          // 1792 16B granules
            const int r  = id >> 7;
            const int gw = (id >> 2) & 31;
            const int g4 = id & 3;
            const int gr = r0 - 3 + r;
            if (gr >= 0 && gr < HH) {
                short8 v = *(const short8*)&xsrc[(gr * WW + gw) * 32 + g4 * 8];
                *(short8*)&xs[r * XS_R_STRIDE + (gw + 3) * XS_C_STRIDE + g4 * 8] = v;
            }
        }
        __syncthreads();

        const ushort_t* wbase =
            wtb + ((size_t)(cc * COUT + oc0 + wm * 64 + ln)) * (KK * 32) + q * 8;

#pragma unroll 1
        for (int kh = 0; kh < K; ++kh) {
            const int rbase = wn * 4 + 3 + (kh - PAD);
#pragma unroll
            for (int kw = 0; kw < K; ++kw) {
                const int khw = kh * K + kw;
                short8 af[4];
#pragma unroll
                for (int mt = 0; mt < 4; ++mt)
                    af[mt] = *(const short8*)&wbase[((size_t)mt * 16 * KK + khw) * 32];
                short8 bf[8];
#pragma unroll
                for (int nt = 0; nt < 8; ++nt) {
                    const int rl = rbase + (nt >> 1);
                    const int c  = (nt & 1) * 16 + ln + 3 + (kw - PAD);
                    bf[nt] = *(const short8*)&xs[rl * XS_R_STRIDE + c * XS_C_STRIDE + q * 8];
                }
#pragma unroll
                for (int mt = 0; mt < 4; ++mt)
#pragma unroll
                    for (int nt = 0; nt < 8; ++nt)
                        acc[mt][nt] = __builtin_amdgcn_mfma_f32_16x16x32_bf16(
                            af[mt], bf[nt], acc[mt][nt], 0, 0, 0);
            }
        }
    }

    // epilogue: C/D layout col = lane&15 (n), row = q*4+reg (m)
    const int ocb = oc0 + wm * 64;
#pragma unroll
    for (int mt = 0; mt < 4; ++mt) {
#pragma unroll
        for (int i = 0; i < 4; ++i) {
            const int oc = ocb + mt * 16 + q * 4 + i;
            const float ev = eb[(size_t)cls * COUT + oc];
            float* ob = out + ((size_t)(b * COUT + oc)) * HW + r0 * WW;
#pragma unroll
            for (int nt = 0; nt < 8; ++nt) {
                const int p = wn * 128 + nt * 16 + ln;
                ob[p] = acc[mt][nt][i] + ev;
            }
        }
    }
}

__global__ __launch_bounds__(256, 2) void conv_mfma(
    const ushort_t* __restrict__ xt, const ushort_t* __restrict__ wt,
    const int* __restrict__ y, const int* __restrict__ arc,
    const float* __restrict__ e0, const float* __restrict__ e1,
    const float* __restrict__ e2, const float* __restrict__ e3,
    float* __restrict__ out) {
    __shared__ ushort_t xs[XS_ELEMS];
    const int blk  = blockIdx.x;
    const int b    = blk & 63;            // sample fastest -> CU mix of branches
    const int tile = blk >> 6;
    const int oc0  = (tile & 1) * 128;
    const int r0   = (tile >> 1) * 8;
    const int a    = __builtin_amdgcn_readfirstlane(arc[b]);
    const int cls  = __builtin_amdgcn_readfirstlane(y[b]);
    switch (a) {
        case 0:  conv_body<1>(xt, wt + WT_OFF_0, e0, b, cls, oc0, r0, out, xs); break;
        case 1:  conv_body<3>(xt, wt + WT_OFF_1, e1, b, cls, oc0, r0, out, xs); break;
        case 2:  conv_body<5>(xt, wt + WT_OFF_2, e2, b, cls, oc0, r0, out, xs); break;
        default: conv_body<7>(xt, wt + WT_OFF_3, e3, b, cls, oc0, r0, out, xs); break;
    }
}

// ---------------- fallback (round-1 direct conv) if ws too small ----------------
__global__ __launch_bounds__(256) void cond_conv_direct(
    const float* __restrict__ x, const int* __restrict__ y,
    const int* __restrict__ arc,
    const float* __restrict__ w0, const float* __restrict__ e0,
    const float* __restrict__ w1, const float* __restrict__ e1,
    const float* __restrict__ w2, const float* __restrict__ e2,
    const float* __restrict__ w3, const float* __restrict__ e3,
    float* __restrict__ out) {
    const int b   = blockIdx.x >> 4;
    const int o0  = (blockIdx.x & 15) << 4;
    const int tid = threadIdx.x;
    const int col  = tid & 31;
    const int row0 = tid >> 5;
    int a   = __builtin_amdgcn_readfirstlane(arc[b]);
    int cls = __builtin_amdgcn_readfirstlane(y[b]);
    const int k   = (a == 0) ? 1 : (a == 1) ? 3 : (a == 2) ? 5 : 7;
    const int kk  = k * k;
    const int pad = k >> 1;
    const float* __restrict__ wp = (a == 0) ? w0 : (a == 1) ? w1 : (a == 2) ? w2 : w3;
    const float* __restrict__ ep = (a == 0) ? e0 : (a == 1) ? e1 : (a == 2) ? e2 : e3;
    __shared__ float xsh[8 * HW];
    float acc[16][4];
#pragma unroll
    for (int o = 0; o < 16; ++o)
#pragma unroll
        for (int p = 0; p < 4; ++p) acc[o][p] = 0.f;
    const float* xb = x + (size_t)b * CIN * HW;
    for (int c0 = 0; c0 < CIN; c0 += 8) {
        __syncthreads();
        const float4* src = (const float4*)(xb + c0 * HW);
        float4* dst = (float4*)xsh;
#pragma unroll
        for (int i = 0; i < 8; ++i) dst[tid + (i << 8)] = src[tid + (i << 8)];
        __syncthreads();
        for (int kh = 0; kh < k; ++kh) {
            const int dh = kh - pad;
            int raddr[4]; bool rok[4];
#pragma unroll
            for (int p = 0; p < 4; ++p) {
                const int rr = row0 + 8 * p + dh;
                rok[p] = (rr >= 0) && (rr < HH);
                raddr[p] = (rok[p] ? rr : 0) * WW;
            }
            for (int kw = 0; kw < k; ++kw) {
                const int cc2 = col + kw - pad;
                const bool cok = (cc2 >= 0) && (cc2 < WW);
                const int cofs = cok ? cc2 : 0;
                const int khw = kh * k + kw;
#pragma unroll
                for (int ci = 0; ci < 8; ++ci) {
                    float xv[4];
#pragma unroll
                    for (int p = 0; p < 4; ++p) {
                        const float v = xsh[ci * HW + raddr[p] + cofs];
                        xv[p] = (rok[p] && cok) ? v : 0.f;
                    }
                    const float* wb = wp + (size_t)o0 * CIN * kk + (size_t)(c0 + ci) * kk + khw;
#pragma unroll
                    for (int o = 0; o < 16; ++o) {
                        const float wsv = wb[(size_t)o * CIN * kk];
#pragma unroll
                        for (int p = 0; p < 4; ++p) acc[o][p] += wsv * xv[p];
                    }
                }
            }
        }
    }
    const float* erow = ep + (size_t)cls * COUT + o0;
    float* ob = out + ((size_t)b * COUT + o0) * HW;
#pragma unroll
    for (int o = 0; o < 16; ++o) {
        const float ev = erow[o];
#pragma unroll
        for (int p = 0; p < 4; ++p)
            ob[o * HW + (row0 + 8 * p) * WW + col] = acc[o][p] + ev;
    }
}

extern "C" void kernel_launch(void* const* d_in, const int* in_sizes, int n_in,
                              void* d_out, int out_size, void* d_ws, size_t ws_size,
                              hipStream_t stream) {
    const float* x   = (const float*)d_in[0];
    const int*   y   = (const int*)  d_in[1];
    const int*   arc = (const int*)  d_in[2];
    const float* w0  = (const float*)d_in[3];
    const float* e0  = (const float*)d_in[4];
    const float* w1  = (const float*)d_in[5];
    const float* e1  = (const float*)d_in[6];
    const float* w2  = (const float*)d_in[7];
    const float* e2  = (const float*)d_in[8];
    const float* w3  = (const float*)d_in[9];
    const float* e3  = (const float*)d_in[10];
    float* out = (float*)d_out;

    if (ws_size >= WS_NEEDED) {
        ushort_t* xt = (ushort_t*)d_ws;
        ushort_t* wt = xt + XT_ELEMS;
        // x transform: 64*8*1024 threads
        hipLaunchKernelGGL(px_kernel, dim3(2048), dim3(256), 0, stream, x, xt);
        // w transforms
        const int tot1 = 8 * 256 * 1 * 32, tot3 = 8 * 256 * 9 * 32;
        const int tot5 = 8 * 256 * 25 * 32, tot7 = 8 * 256 * 49 * 32;
        hipLaunchKernelGGL(pw_kernel, dim3((tot1 + 255) / 256), dim3(256), 0, stream, w0, wt + WT_OFF_0, 1,  tot1);
        hipLaunchKernelGGL(pw_kernel, dim3((tot3 + 255) / 256), dim3(256), 0, stream, w1, wt + WT_OFF_1, 9,  tot3);
        hipLaunchKernelGGL(pw_kernel, dim3((tot5 + 255) / 256), dim3(256), 0, stream, w2, wt + WT_OFF_2, 25, tot5);
        hipLaunchKernelGGL(pw_kernel, dim3((tot7 + 255) / 256), dim3(256), 0, stream, w3, wt + WT_OFF_3, 49, tot7);
        // main
        hipLaunchKernelGGL(conv_mfma, dim3(512), dim3(256), 0, stream,
                           xt, wt, y, arc, e0, e1, e2, e3, out);
    } else {
        const int B = in_sizes[1];
        hipLaunchKernelGGL(cond_conv_direct, dim3(B * 16), dim3(256), 0, stream,
                           x, y, arc, w0, e0, w1, e1, w2, e2, w3, e3, out);
    }
}